// Round 3
// baseline (65113.525 us; speedup 1.0000x reference)
//
#include <hip/hip_runtime.h>
#include <cstdint>
#include <cstddef>

typedef __attribute__((ext_vector_type(8))) short bf16x8;
typedef __attribute__((ext_vector_type(4))) float f32x4;
typedef uint16_t u16;
typedef uint32_t u32;
typedef uint64_t u64;

#define NS 4096

// ---------------- fixed workspace layout (bytes) ----------------
// hXM: tagged h exchange through MALL (agent scope — the only proven-coherent
// cross-WG path on this part), pair-major [4 bufs][4 chains][128 p][16 r] u64
#define OFF_HX4    ((size_t)0)                        // 256 KB (unused, kept for layout stability)
#define OFF_HXM    ((size_t)262144)                   // 256 KB
#define OFF_STATE  ((size_t)524288)                   // 128 KB: c then h, f32 [64][256]
#define OFF_WHT    ((size_t)655360)                   // 512 KB
#define OFF_WXTH   (OFF_WHT   + (size_t)524288)
#define OFF_WXTL   (OFF_WXTH  + (size_t)262144)
#define OFF_WEF1H  (OFF_WXTL  + (size_t)262144)
#define OFF_WEF1L  (OFF_WEF1H + (size_t)32768)
#define OFF_WEF3H  (OFF_WEF1L + (size_t)32768)
#define OFF_WEF3L  (OFF_WEF3H + (size_t)65536)
#define OFF_CH     ((size_t)2*1024*1024)              // chunk region
// per-step: s hi/lo + x hi/lo + e1 hi/lo (6x16KB) + xw f32 (256KB) + j f32 (64KB)
#define CH_BYTES_PER_SC ((size_t)425984)

template<int N> struct ic { static constexpr int value = N; };

// ---------------- helpers ----------------
static __device__ __forceinline__ float bf2f(u16 u){
  union { uint32_t i; float f; } v; v.i = ((uint32_t)u) << 16; return v.f;
}
static __device__ __forceinline__ u16 f2bf(float f){
  union { float f; uint32_t u; } v; v.f = f;
  uint32_t r = v.u + 0x7fffu + ((v.u >> 16) & 1u);
  return (u16)(r >> 16);
}
static __device__ __forceinline__ float sigmoid_f(float x){
  return 1.f / (1.f + __expf(-x));
}
static __device__ __forceinline__ float tanh_f(float x){
  x = fminf(15.f, fmaxf(-15.f, x));
  float e = __expf(2.f * x);
  return 1.f - 2.f / (e + 1.f);
}
// MALL-path (agent-scope) atomics: bypass L1+L2 to the device coherence point.
static __device__ __forceinline__ u64 agld64(const u64* p){
  return __hip_atomic_load(p, __ATOMIC_RELAXED, __HIP_MEMORY_SCOPE_AGENT);
}
static __device__ __forceinline__ void agst64(u64* p, u64 v){
  __hip_atomic_store(p, v, __ATOMIC_RELAXED, __HIP_MEMORY_SCOPE_AGENT);
}

// ---------------- K0: weight transpose/convert (hi/lo split for GEMM weights) ----------------
__global__ void k_prep(const float* __restrict__ Wh, const float* __restrict__ Wx,
                       const float* __restrict__ Wef1, const float* __restrict__ Wef3,
                       u16* __restrict__ WhT,
                       u16* __restrict__ WxTh, u16* __restrict__ WxTl,
                       u16* __restrict__ Wef1h, u16* __restrict__ Wef1l,
                       u16* __restrict__ Wef3h, u16* __restrict__ Wef3l){
  int idx = blockIdx.x*256 + threadIdx.x;
  if (idx < 262144){ int n = idx>>8, k = idx&255; WhT[idx] = f2bf(Wh[k*1024+n]); return; }
  idx -= 262144;
  if (idx < 131072){
    int n = idx>>7, k = idx&127; float w = Wx[k*1024+n];
    u16 h = f2bf(w); WxTh[idx] = h; WxTl[idx] = f2bf(w - bf2f(h)); return;
  }
  idx -= 131072;
  if (idx < 16384){
    int n = idx>>7, k = idx&127; float w = Wef1[k*128+n];
    u16 h = f2bf(w); Wef1h[idx] = h; Wef1l[idx] = f2bf(w - bf2f(h)); return;
  }
  idx -= 16384;
  if (idx < 32768){
    int n = idx>>7, k = idx&127; float w = Wef3[k*256+n];
    u16 h = f2bf(w); Wef3h[idx] = h; Wef3l[idx] = f2bf(w - bf2f(h)); return;
  }
}

// seed exchange buffer[3], tag 0 (pair-major [p][r])
__global__ void k_seed(const float* __restrict__ h0, u64* __restrict__ hXM){
  int idx = blockIdx.x*256 + threadIdx.x;   // 0..8191
  int gr = idx >> 7, p = idx & 127;
  u16 he = f2bf(h0[(size_t)gr*256 + 2*p]);
  u16 ho = f2bf(h0[(size_t)gr*256 + 2*p + 1]);
  int g = gr >> 4, r = gr & 15;
  u64 v = (u64)he | ((u64)ho << 16);        // tag 0
  hXM[(size_t)(3*4 + g)*2048 + p*16 + r] = v;
}

// ---------------- K1: embedding (chunked): rows m = sc*64 + b, hi/lo outputs ----------------
__global__ __launch_bounds__(256) void k_embed(
    const float* __restrict__ event, const float* __restrict__ vc, const float* __restrict__ vn,
    const float* __restrict__ Ve, const float* __restrict__ Vc, const float* __restrict__ Vn,
    u16* __restrict__ sHi, u16* __restrict__ sLo,
    u16* __restrict__ xHi, u16* __restrict__ xLo, int c0){
  __shared__ float VeL[64*128];
  __shared__ float VcL[32*128];
  __shared__ float VnL[16*128];
  __shared__ float evL[16*64];
  __shared__ float vcL[16*32];
  __shared__ float vnL[16*16];
  const int tid = threadIdx.x;
  const int sc = blockIdx.x >> 2;
  const int b0 = (blockIdx.x & 3) * 16;
  const int ss = c0 + sc;
  for (int i = tid; i < 64*128; i += 256) VeL[i] = Ve[i];
  for (int i = tid; i < 32*128; i += 256) VcL[i] = Vc[i];
  for (int i = tid; i < 16*128; i += 256) VnL[i] = Vn[i];
  for (int i = tid; i < 16*64; i += 256)
    evL[i] = event[((size_t)(b0 + (i>>6))*4096 + ss)*64 + (i&63)];
  for (int i = tid; i < 16*32; i += 256)
    vcL[i] = vc[((size_t)(b0 + (i>>5))*4096 + ss)*32 + (i&31)];
  for (int i = tid; i < 16*16; i += 256)
    vnL[i] = vn[((size_t)(b0 + (i>>4))*4096 + ss)*16 + (i&15)];
  __syncthreads();
  const int n = tid & 127, half = tid >> 7;
  for (int r = half; r < 16; r += 2){
    float sd = 0.f, cd = 0.f, nd = 0.f;
    #pragma unroll 8
    for (int k = 0; k < 64; ++k) sd = fmaf(evL[r*64+k], VeL[k*128+n], sd);
    #pragma unroll 8
    for (int k = 0; k < 32; ++k) cd = fmaf(vcL[r*32+k], VcL[k*128+n], cd);
    #pragma unroll 8
    for (int k = 0; k < 16; ++k) nd = fmaf(vnL[r*16+k], VnL[k*128+n], nd);
    float x = sd + 2.f*(cd + tanh_f(nd));
    size_t o = ((size_t)sc*64 + b0 + r)*128 + n;
    u16 sh = f2bf(sd); sHi[o] = sh; sLo[o] = f2bf(sd - bf2f(sh));
    u16 xh = f2bf(x);  xHi[o] = xh; xLo[o] = f2bf(x  - bf2f(xh));
  }
}

// ---------------- K2: split-bf16 ("bf16x3") MFMA GEMM, K=128, act+bias epilogue ----------------
// OUTKIND 0: f32 C[m][N]   1: f32 xw gate-interleaved [m][hid][gate]   2: hi/lo bf16 planes [m][N]
template<int ACT, int OUTKIND, int NTILES>
__global__ __launch_bounds__(256) void k_gemm(
    const u16* __restrict__ Ahi, const u16* __restrict__ Alo,
    const u16* __restrict__ BTh, const u16* __restrict__ BTl,
    const float* __restrict__ bias,
    float* __restrict__ CoutF, u16* __restrict__ CoutHi, u16* __restrict__ CoutLo){
  __shared__ u16 aLh[4][16*136];
  __shared__ u16 aLl[4][16*136];
  const int tid = threadIdx.x, lane = tid & 63, w = tid >> 6;
  const int c15 = lane & 15, q4 = lane >> 4;
  const size_t mbase = (size_t)blockIdx.x*64 + (size_t)w*16;
  const u16* Aph = Ahi + mbase*128;
  const u16* Apl = Alo + mbase*128;
  #pragma unroll
  for (int i = 0; i < 4; ++i){
    int row = q4 + i*4;
    *(bf16x8*)(&aLh[w][row*136 + c15*8]) = *(const bf16x8*)(Aph + row*128 + c15*8);
    *(bf16x8*)(&aLl[w][row*136 + c15*8]) = *(const bf16x8*)(Apl + row*128 + c15*8);
  }
  __syncthreads();
  bf16x8 ah[4], al[4];
  #pragma unroll
  for (int q = 0; q < 4; ++q){
    ah[q] = *(const bf16x8*)(&aLh[w][c15*136 + q*32 + q4*8]);
    al[q] = *(const bf16x8*)(&aLl[w][c15*136 + q*32 + q4*8]);
  }
  const u16* Bph = BTh + c15*128 + q4*8;
  const u16* Bpl = BTl + c15*128 + q4*8;

  bf16x8 bh[4], bl[4], bhn[4], bln[4];
  #pragma unroll
  for (int q = 0; q < 4; ++q){ bh[q] = *(const bf16x8*)(Bph + q*32); bl[q] = *(const bf16x8*)(Bpl + q*32); }

  for (int nt = 0; nt < NTILES; ++nt){
    if (nt + 1 < NTILES){
      #pragma unroll
      for (int q = 0; q < 4; ++q){
        bhn[q] = *(const bf16x8*)(Bph + (nt+1)*2048 + q*32);
        bln[q] = *(const bf16x8*)(Bpl + (nt+1)*2048 + q*32);
      }
    }
    f32x4 acc = (f32x4){0.f,0.f,0.f,0.f};
    #pragma unroll
    for (int q = 0; q < 4; ++q){
      acc = __builtin_amdgcn_mfma_f32_16x16x32_bf16(al[q], bh[q], acc, 0, 0, 0);
      acc = __builtin_amdgcn_mfma_f32_16x16x32_bf16(ah[q], bl[q], acc, 0, 0, 0);
      acc = __builtin_amdgcn_mfma_f32_16x16x32_bf16(ah[q], bh[q], acc, 0, 0, 0);
    }
    const int n = nt*16 + c15;
    const float bv = bias[n];
    #pragma unroll
    for (int i = 0; i < 4; ++i){
      float v = acc[i] + bv;
      if (ACT == 1) v = tanh_f(v);
      else if (ACT == 2) v = sigmoid_f(v);
      const size_t m = mbase + q4*4 + i;
      if (OUTKIND == 0){
        CoutF[m*(size_t)(NTILES*16) + n] = v;
      } else if (OUTKIND == 1){
        CoutF[m*1024 + (size_t)(n & 255)*4 + (size_t)(n >> 8)] = v;
      } else {
        size_t o = m*(size_t)(NTILES*16) + n;
        u16 hh = f2bf(v); CoutHi[o] = hh; CoutLo[o] = f2bf(v - bf2f(hh));
      }
    }
    #pragma unroll
    for (int q = 0; q < 4; ++q){ bh[q] = bhn[q]; bl[q] = bln[q]; }
  }
}

// ---------------- K3: the scan — 4 WGs, 4 interleaved chains, MALL prefetch ----------------
// WG s (blockIdx.x = 0..3) owns hid cols s*64..s*64+63. It processes the 4
// INDEPENDENT batch-group chains round-robin: sub-steps (t,0)(t,1)(t,2)(t,3).
// The h exchange stays on the proven agent-scope (MALL) tagged-word protocol,
// but each consume uses a prefetch issued 2 sub-steps earlier — producers
// stored that data 4 sub-steps earlier, so in steady state the tag check hits
// on the first try and the ~900cy MALL latency is hidden under the other
// chains' compute. No barriers, no XCD-placement assumptions (3 prior rounds
// showed same-XCD L2 coherence is not reachable from HIP source here).
// Slow path: per-lane re-poll until tags match (correct under any timing).
// Ring safety: consume of step t needs tag t in slot (t+3)&3; overwrite of
// that slot carries tag t+4, which requires stores of step t+3 — impossible
// while any WG is stuck before t (dependency bounds skew < 3 steps).
__global__ __launch_bounds__(256, 1) void k_scan(
    const u16* __restrict__ WhT, const float* __restrict__ xwG, const float* __restrict__ jG,
    const float* __restrict__ Wc, const float* __restrict__ h0, const float* __restrict__ c0in,
    const float* __restrict__ Wlin, const float* __restrict__ blin,
    u64* __restrict__ hXM, float* __restrict__ stateF,
    float* __restrict__ out, int T0, int SC, int FINAL)
{
  const int s    = blockIdx.x;      // slot: hid-col quarter
  const int tid  = threadIdx.x;
  const int lane = tid & 63;
  const int w    = tid >> 6;
  const int c15  = lane & 15;
  const int q4   = lane >> 4;
  const int ghid = s*64 + w*16 + c15;
  const int FIRST = (T0 == 0);

  // Wh fragments for this wave's 16 cols x 4 gates (128 VGPRs)
  bf16x8 Bf[4][8];
  {
    const u16* bp = WhT + (size_t)ghid*256 + q4*8;
    #pragma unroll
    for (int gt = 0; gt < 4; ++gt)
      #pragma unroll
      for (int q = 0; q < 8; ++q)
        Bf[gt][q] = *(const bf16x8*)(bp + (size_t)gt*65536 + q*32);
  }

  // per-chain state: rows G*16 + q4*4 + i, col ghid
  float creg[4][4], hreg[4][4];
  #pragma unroll
  for (int G = 0; G < 4; ++G){
    #pragma unroll
    for (int i = 0; i < 4; ++i){
      int r = q4*4 + i;
      if (FIRST){
        creg[G][i] = c0in[(size_t)(G*16 + r)*256 + ghid];
        hreg[G][i] = h0[(size_t)(G*16 + r)*256 + ghid];
      } else {
        creg[G][i] = stateF[(size_t)(G*16 + r)*256 + ghid];
        hreg[G][i] = stateF[16384 + (size_t)(G*16 + r)*256 + ghid];
      }
    }
  }
  const float wc0 = Wc[ghid], wc1 = Wc[256 + ghid], wc2 = Wc[512 + ghid];
  const int P = s*32 + w*8 + (c15 >> 1);   // col-pair index this lane stores

  // prefetch slots: E used by chains 0,2; O by chains 1,3 (static names, rule #20)
  u64   pfE[8][4], pfO[8][4];
  f32x4 xwE[4],    xwO[4];
  float jvE[4],    jvO[4];

  auto issueH = [&](u64 (&pf)[8][4], int Q, int tn){
    const unsigned Tq = (unsigned)(T0 + tn);
    const u64* bM = hXM + (size_t)(((Tq + 3) & 3)*4 + Q)*2048 + c15;
    #pragma unroll
    for (int q = 0; q < 8; ++q)
      #pragma unroll
      for (int jj = 0; jj < 4; ++jj)
        pf[q][jj] = agld64(bM + (q*16 + q4*4 + jj)*16);
  };
  auto issueXW = [&](f32x4 (&xq)[4], float (&jv)[4], int Q, int tn){
    const float* xwp = xwG + ((size_t)tn*64 + Q*16)*1024 + (size_t)ghid*4;
    const float* jp  = jG  + ((size_t)tn*64 + Q*16)*256 + ghid;
    #pragma unroll
    for (int i = 0; i < 4; ++i){
      xq[i] = *(const f32x4*)(xwp + (size_t)(q4*4 + i)*1024);
      jv[i] = jp[(size_t)(q4*4 + i)*256];
    }
  };

  // one sub-step of chain G at local step t (G compile-time via ic<>)
  auto sub = [&](auto Gc, int t, u64 (&pf)[8][4], f32x4 (&xq)[4], float (&jv)[4]){
    constexpr int G = decltype(Gc)::value;
    const unsigned T = (unsigned)(T0 + t);

    // consume: tag-check prefetched words; rare slow path re-polls (per-lane)
    bool ok = true;
    #pragma unroll
    for (int q = 0; q < 8; ++q)
      #pragma unroll
      for (int jj = 0; jj < 4; ++jj)
        ok &= ((u32)(pf[q][jj] >> 32) == T);
    if (!ok){
      const u64* bM = hXM + (size_t)(((T + 3) & 3)*4 + G)*2048 + c15;
      do {
        ok = true;
        #pragma unroll
        for (int q = 0; q < 8; ++q)
          #pragma unroll
          for (int jj = 0; jj < 4; ++jj){
            pf[q][jj] = agld64(bM + (q*16 + q4*4 + jj)*16);
            ok &= ((u32)(pf[q][jj] >> 32) == T);
          }
      } while (!ok);
    }

    // repack lo-halves -> A fragments
    bf16x8 Af[8];
    #pragma unroll
    for (int q = 0; q < 8; ++q){
      union { u32 dd[4]; bf16x8 v; } cv;
      #pragma unroll
      for (int jj = 0; jj < 4; ++jj) cv.dd[jj] = (u32)pf[q][jj];
      Af[q] = cv.v;
    }

    // pf regs now dead: reissue for the chain consumed 2 sub-steps from now
    constexpr int QN = (G + 2) & 3;
    const int tn = t + (G >= 2 ? 1 : 0);
    if (tn < SC) issueH(pf, QN, tn);

    f32x4 acc[4];
    #pragma unroll
    for (int gt = 0; gt < 4; ++gt) acc[gt] = (f32x4){0.f,0.f,0.f,0.f};
    #pragma unroll
    for (int q = 0; q < 8; ++q)
      #pragma unroll
      for (int gt = 0; gt < 4; ++gt)
        acc[gt] = __builtin_amdgcn_mfma_f32_16x16x32_bf16(Af[q], Bf[gt][q], acc[gt], 0, 0, 0);

    u16 hb[4];
    #pragma unroll
    for (int i = 0; i < 4; ++i){
      float ip = acc[0][i] + xq[i][0] + creg[G][i]*wc0;
      float fp = acc[1][i] + xq[i][1] + creg[G][i]*wc1;
      float gp = acc[2][i] + xq[i][2];
      float op = acc[3][i] + xq[i][3] + creg[G][i]*wc2;
      float it2 = sigmoid_f(ip);
      float ft = sigmoid_f(fp);
      float gt = tanh_f(gp);
      float ot = sigmoid_f(op);
      float chat = ft*creg[G][i] + it2*gt;
      float cn = creg[G][i] + jv[i]*(chat - creg[G][i]);
      float hhat = ot*tanh_f(chat);
      float hn = hreg[G][i] + jv[i]*(hhat - hreg[G][i]);
      creg[G][i] = cn; hreg[G][i] = hn;
      hb[i] = f2bf(hn);
    }

    // xq/jv regs dead: reissue for the same upcoming consume
    if (tn < SC) issueXW(xq, jv, QN, tn);

    // pack + store own slice, tag T+1 (agent scope)
    u32 a = (u32)hb[0] | ((u32)hb[1] << 16);
    u32 b = (u32)hb[2] | ((u32)hb[3] << 16);
    u32 pa = (u32)__shfl_xor((int)a, 1, 64);
    u32 pb = (u32)__shfl_xor((int)b, 1, 64);
    u64* hwM = hXM + (size_t)((T & 3)*4 + G)*2048 + (size_t)P*16;
    const u64 tag = ((u64)(T + 1)) << 32;
    if ((lane & 1) == 0){
      agst64(hwM + q4*4 + 0, tag | (u64)((a & 0xffffu) | ((pa & 0xffffu) << 16)));
      agst64(hwM + q4*4 + 1, tag | (u64)((a >> 16) | (pa & 0xffff0000u)));
    } else {
      agst64(hwM + q4*4 + 2, tag | (u64)((pb & 0xffffu) | ((b & 0xffffu) << 16)));
      agst64(hwM + q4*4 + 3, tag | (u64)((pb >> 16) | (b & 0xffff0000u)));
    }
    asm volatile("" ::: "memory");   // keep stores inside this sub-step
  };

  // prologue: prefetch chains 0,1 step 0 (data seeded / stored by prev dispatch)
  issueH(pfE, 0, 0); issueXW(xwE, jvE, 0, 0);
  issueH(pfO, 1, 0); issueXW(xwO, jvO, 1, 0);

  for (int t = 0; t < SC; ++t){
    sub(ic<0>{}, t, pfE, xwE, jvE);
    sub(ic<1>{}, t, pfO, xwO, jvO);
    sub(ic<2>{}, t, pfE, xwE, jvE);
    sub(ic<3>{}, t, pfO, xwO, jvO);
  }

  // persist f32 state for next chunk (kernel-boundary flush makes it visible)
  if (!FINAL){
    #pragma unroll
    for (int G = 0; G < 4; ++G)
      #pragma unroll
      for (int i = 0; i < 4; ++i){
        int r = q4*4 + i;
        stateF[(size_t)(G*16 + r)*256 + ghid] = creg[G][i];
        stateF[16384 + (size_t)(G*16 + r)*256 + ghid] = hreg[G][i];
      }
  }

  // epilogue on final chunk: out = h_T @ Wlin + blin ; WG s handles rows s*16..+15
  if (FINAL){
    __shared__ float hF[16*256];
    const unsigned tgt = (unsigned)NS;     // h_T carries tag NS in buffer 3
    for (int idx = tid; idx < 2048; idx += 256){
      int r = idx >> 7, p = idx & 127;
      const u64* ap = hXM + (size_t)(3*4 + s)*2048 + p*16 + r;
      u64 v;
      do { v = agld64(ap); } while ((u32)(v >> 32) != tgt);
      hF[r*256 + 2*p]     = bf2f((u16)v);
      hF[r*256 + 2*p + 1] = bf2f((u16)(v >> 16));
    }
    __syncthreads();
    for (int idx = tid; idx < 1024; idx += 256){
      int r = idx >> 6, dcol = idx & 63;
      float aacc = blin[dcol];
      for (int k = 0; k < 256; ++k)
        aacc = fmaf(hF[r*256 + k], Wlin[k*64 + dcol], aacc);
      out[(size_t)(s*16 + r)*64 + dcol] = aacc;
    }
  }
}

// ---------------- host ----------------
extern "C" void kernel_launch(void* const* d_in, const int* in_sizes, int n_in,
                              void* d_out, int out_size, void* d_ws, size_t ws_size,
                              hipStream_t stream)
{
  (void)in_sizes; (void)n_in;
  const float* event = (const float*)d_in[0];
  const float* vc    = (const float*)d_in[2];
  const float* vn    = (const float*)d_in[3];
  const float* h0    = (const float*)d_in[4];
  const float* c0v   = (const float*)d_in[5];
  const float* Wx    = (const float*)d_in[6];
  const float* Wh    = (const float*)d_in[7];
  const float* Wc    = (const float*)d_in[8];
  const float* bias  = (const float*)d_in[9];
  const float* Ve    = (const float*)d_in[10];
  const float* Vc    = (const float*)d_in[11];
  const float* Vn    = (const float*)d_in[12];
  const float* Wlin  = (const float*)d_in[13];
  const float* blin  = (const float*)d_in[14];
  const float* Wef1  = (const float*)d_in[15];
  const float* bef1  = (const float*)d_in[16];
  const float* Wef3  = (const float*)d_in[17];
  const float* bef3  = (const float*)d_in[18];

  int SC = 0;
  const int cands[9] = {4096, 2048, 1024, 512, 256, 128, 64, 32, 16};
  for (int i = 0; i < 9; ++i){
    if (OFF_CH + (size_t)cands[i]*CH_BYTES_PER_SC <= ws_size){ SC = cands[i]; break; }
  }
  if (SC == 0){
    hipMemsetAsync(d_out, 0, (size_t)out_size*sizeof(float), stream);
    return;
  }
  const int C = NS / SC;

  char* ws = (char*)d_ws;
  u64*   hXM    = (u64*)(ws + OFF_HXM);
  float* stateF = (float*)(ws + OFF_STATE);
  u16* WhT   = (u16*)(ws + OFF_WHT);
  u16* WxTh  = (u16*)(ws + OFF_WXTH);
  u16* WxTl  = (u16*)(ws + OFF_WXTL);
  u16* Wef1h = (u16*)(ws + OFF_WEF1H);
  u16* Wef1l = (u16*)(ws + OFF_WEF1L);
  u16* Wef3h = (u16*)(ws + OFF_WEF3H);
  u16* Wef3l = (u16*)(ws + OFF_WEF3L);
  char* ch = ws + OFF_CH;
  u16* sHi  = (u16*)ch;
  u16* sLo  = (u16*)(ch + (size_t)SC*16384);
  u16* xHi  = (u16*)(ch + (size_t)SC*32768);
  u16* xLo  = (u16*)(ch + (size_t)SC*49152);
  u16* e1Hi = (u16*)(ch + (size_t)SC*65536);
  u16* e1Lo = (u16*)(ch + (size_t)SC*81920);
  float* xwG = (float*)(ch + (size_t)SC*98304);
  float* jG  = (float*)(ch + (size_t)SC*360448);

  k_prep<<<1728, 256, 0, stream>>>(Wh, Wx, Wef1, Wef3, WhT, WxTh, WxTl,
                                   Wef1h, Wef1l, Wef3h, Wef3l);
  k_seed<<<32, 256, 0, stream>>>(h0, hXM);

  for (int c = 0; c < C; ++c){
    const int c0 = c * SC;
    k_embed<<<SC*4, 256, 0, stream>>>(event, vc, vn, Ve, Vc, Vn, sHi, sLo, xHi, xLo, c0);
    k_gemm<0,1,64><<<SC, 256, 0, stream>>>(xHi, xLo, WxTh, WxTl, bias, xwG, nullptr, nullptr);
    k_gemm<1,2,8><<<SC, 256, 0, stream>>>(sHi, sLo, Wef1h, Wef1l, bef1, nullptr, e1Hi, e1Lo);
    k_gemm<2,0,16><<<SC, 256, 0, stream>>>(e1Hi, e1Lo, Wef3h, Wef3l, bef3, jG, nullptr, nullptr);
    k_scan<<<4, 256, 0, stream>>>(WhT, xwG, jG, Wc, h0, c0v, Wlin, blin,
                                  hXM, stateF, (float*)d_out, c0, SC, (c == C-1) ? 1 : 0);
  }
}

// Round 4
// 19740.576 us; speedup vs baseline: 3.2985x; 3.2985x over previous
//
#include <hip/hip_runtime.h>
#include <cstdint>
#include <cstddef>

typedef __attribute__((ext_vector_type(8))) short bf16x8;
typedef __attribute__((ext_vector_type(4))) float f32x4;
typedef uint16_t u16;
typedef uint32_t u32;
typedef uint64_t u64;

#define NS 4096

// ---------------- fixed workspace layout (bytes) ----------------
// hXM: tagged h exchange through MALL (agent scope — the only proven-coherent
// cross-WG path on this part), pair-major [4 bufs][4 g][128 p][16 r] u64
#define OFF_HX4    ((size_t)0)                        // 256 KB (unused, layout stability)
#define OFF_HXM    ((size_t)262144)                   // 256 KB
#define OFF_STATE  ((size_t)524288)                   // 128 KB: c then h, f32 [64][256]
#define OFF_WHT    ((size_t)655360)                   // 512 KB
#define OFF_WXTH   (OFF_WHT   + (size_t)524288)
#define OFF_WXTL   (OFF_WXTH  + (size_t)262144)
#define OFF_WEF1H  (OFF_WXTL  + (size_t)262144)
#define OFF_WEF1L  (OFF_WEF1H + (size_t)32768)
#define OFF_WEF3H  (OFF_WEF1L + (size_t)32768)
#define OFF_WEF3L  (OFF_WEF3H + (size_t)65536)
#define OFF_CH     ((size_t)2*1024*1024)              // chunk region
// per-step: s hi/lo + x hi/lo + e1 hi/lo (6x16KB) + xw f32 (256KB) + j f32 (64KB)
#define CH_BYTES_PER_SC ((size_t)425984)

// ---------------- helpers ----------------
static __device__ __forceinline__ float bf2f(u16 u){
  union { uint32_t i; float f; } v; v.i = ((uint32_t)u) << 16; return v.f;
}
static __device__ __forceinline__ u16 f2bf(float f){
  union { float f; uint32_t u; } v; v.f = f;
  uint32_t r = v.u + 0x7fffu + ((v.u >> 16) & 1u);
  return (u16)(r >> 16);
}
static __device__ __forceinline__ float sigmoid_f(float x){
  return 1.f / (1.f + __expf(-x));
}
static __device__ __forceinline__ float tanh_f(float x){
  x = fminf(15.f, fmaxf(-15.f, x));
  float e = __expf(2.f * x);
  return 1.f - 2.f / (e + 1.f);
}
// MALL-path (agent-scope) atomic load: bypass L1+L2 to the device coherence point.
static __device__ __forceinline__ u64 agld64(const u64* p){
  return __hip_atomic_load(p, __ATOMIC_RELAXED, __HIP_MEMORY_SCOPE_AGENT);
}
// Publish via atomic swap: an RMW is PERFORMED AT the coherence point and
// cannot sit in a write-coalescing buffer — the experiment this round is
// whether store-drain latency was the dominant term of the 3.3us/step.
static __device__ __forceinline__ void agxchg64(u64* p, u64 v){
  (void)__hip_atomic_exchange(p, v, __ATOMIC_RELAXED, __HIP_MEMORY_SCOPE_AGENT);
}

// ---------------- K0: weight transpose/convert (hi/lo split for GEMM weights) ----------------
__global__ void k_prep(const float* __restrict__ Wh, const float* __restrict__ Wx,
                       const float* __restrict__ Wef1, const float* __restrict__ Wef3,
                       u16* __restrict__ WhT,
                       u16* __restrict__ WxTh, u16* __restrict__ WxTl,
                       u16* __restrict__ Wef1h, u16* __restrict__ Wef1l,
                       u16* __restrict__ Wef3h, u16* __restrict__ Wef3l){
  int idx = blockIdx.x*256 + threadIdx.x;
  if (idx < 262144){ int n = idx>>8, k = idx&255; WhT[idx] = f2bf(Wh[k*1024+n]); return; }
  idx -= 262144;
  if (idx < 131072){
    int n = idx>>7, k = idx&127; float w = Wx[k*1024+n];
    u16 h = f2bf(w); WxTh[idx] = h; WxTl[idx] = f2bf(w - bf2f(h)); return;
  }
  idx -= 131072;
  if (idx < 16384){
    int n = idx>>7, k = idx&127; float w = Wef1[k*128+n];
    u16 h = f2bf(w); Wef1h[idx] = h; Wef1l[idx] = f2bf(w - bf2f(h)); return;
  }
  idx -= 16384;
  if (idx < 32768){
    int n = idx>>7, k = idx&127; float w = Wef3[k*256+n];
    u16 h = f2bf(w); Wef3h[idx] = h; Wef3l[idx] = f2bf(w - bf2f(h)); return;
  }
}

// seed exchange buffer[3], tag 0 (pair-major [p][r])
__global__ void k_seed(const float* __restrict__ h0, u64* __restrict__ hXM){
  int idx = blockIdx.x*256 + threadIdx.x;   // 0..8191
  int gr = idx >> 7, p = idx & 127;
  u16 he = f2bf(h0[(size_t)gr*256 + 2*p]);
  u16 ho = f2bf(h0[(size_t)gr*256 + 2*p + 1]);
  int g = gr >> 4, r = gr & 15;
  u64 v = (u64)he | ((u64)ho << 16);        // tag 0
  hXM[(size_t)(3*4 + g)*2048 + p*16 + r] = v;
}

// ---------------- K1: embedding (chunked): rows m = sc*64 + b, hi/lo outputs ----------------
__global__ __launch_bounds__(256) void k_embed(
    const float* __restrict__ event, const float* __restrict__ vc, const float* __restrict__ vn,
    const float* __restrict__ Ve, const float* __restrict__ Vc, const float* __restrict__ Vn,
    u16* __restrict__ sHi, u16* __restrict__ sLo,
    u16* __restrict__ xHi, u16* __restrict__ xLo, int c0){
  __shared__ float VeL[64*128];
  __shared__ float VcL[32*128];
  __shared__ float VnL[16*128];
  __shared__ float evL[16*64];
  __shared__ float vcL[16*32];
  __shared__ float vnL[16*16];
  const int tid = threadIdx.x;
  const int sc = blockIdx.x >> 2;
  const int b0 = (blockIdx.x & 3) * 16;
  const int ss = c0 + sc;
  for (int i = tid; i < 64*128; i += 256) VeL[i] = Ve[i];
  for (int i = tid; i < 32*128; i += 256) VcL[i] = Vc[i];
  for (int i = tid; i < 16*128; i += 256) VnL[i] = Vn[i];
  for (int i = tid; i < 16*64; i += 256)
    evL[i] = event[((size_t)(b0 + (i>>6))*4096 + ss)*64 + (i&63)];
  for (int i = tid; i < 16*32; i += 256)
    vcL[i] = vc[((size_t)(b0 + (i>>5))*4096 + ss)*32 + (i&31)];
  for (int i = tid; i < 16*16; i += 256)
    vnL[i] = vn[((size_t)(b0 + (i>>4))*4096 + ss)*16 + (i&15)];
  __syncthreads();
  const int n = tid & 127, half = tid >> 7;
  for (int r = half; r < 16; r += 2){
    float sd = 0.f, cd = 0.f, nd = 0.f;
    #pragma unroll 8
    for (int k = 0; k < 64; ++k) sd = fmaf(evL[r*64+k], VeL[k*128+n], sd);
    #pragma unroll 8
    for (int k = 0; k < 32; ++k) cd = fmaf(vcL[r*32+k], VcL[k*128+n], cd);
    #pragma unroll 8
    for (int k = 0; k < 16; ++k) nd = fmaf(vnL[r*16+k], VnL[k*128+n], nd);
    float x = sd + 2.f*(cd + tanh_f(nd));
    size_t o = ((size_t)sc*64 + b0 + r)*128 + n;
    u16 sh = f2bf(sd); sHi[o] = sh; sLo[o] = f2bf(sd - bf2f(sh));
    u16 xh = f2bf(x);  xHi[o] = xh; xLo[o] = f2bf(x  - bf2f(xh));
  }
}

// ---------------- K2: split-bf16 ("bf16x3") MFMA GEMM, K=128, act+bias epilogue ----------------
// OUTKIND 0: f32 C[m][N]   1: f32 xw gate-interleaved [m][hid][gate]   2: hi/lo bf16 planes [m][N]
template<int ACT, int OUTKIND, int NTILES>
__global__ __launch_bounds__(256) void k_gemm(
    const u16* __restrict__ Ahi, const u16* __restrict__ Alo,
    const u16* __restrict__ BTh, const u16* __restrict__ BTl,
    const float* __restrict__ bias,
    float* __restrict__ CoutF, u16* __restrict__ CoutHi, u16* __restrict__ CoutLo){
  __shared__ u16 aLh[4][16*136];
  __shared__ u16 aLl[4][16*136];
  const int tid = threadIdx.x, lane = tid & 63, w = tid >> 6;
  const int c15 = lane & 15, q4 = lane >> 4;
  const size_t mbase = (size_t)blockIdx.x*64 + (size_t)w*16;
  const u16* Aph = Ahi + mbase*128;
  const u16* Apl = Alo + mbase*128;
  #pragma unroll
  for (int i = 0; i < 4; ++i){
    int row = q4 + i*4;
    *(bf16x8*)(&aLh[w][row*136 + c15*8]) = *(const bf16x8*)(Aph + row*128 + c15*8);
    *(bf16x8*)(&aLl[w][row*136 + c15*8]) = *(const bf16x8*)(Apl + row*128 + c15*8);
  }
  __syncthreads();
  bf16x8 ah[4], al[4];
  #pragma unroll
  for (int q = 0; q < 4; ++q){
    ah[q] = *(const bf16x8*)(&aLh[w][c15*136 + q*32 + q4*8]);
    al[q] = *(const bf16x8*)(&aLl[w][c15*136 + q*32 + q4*8]);
  }
  const u16* Bph = BTh + c15*128 + q4*8;
  const u16* Bpl = BTl + c15*128 + q4*8;

  bf16x8 bh[4], bl[4], bhn[4], bln[4];
  #pragma unroll
  for (int q = 0; q < 4; ++q){ bh[q] = *(const bf16x8*)(Bph + q*32); bl[q] = *(const bf16x8*)(Bpl + q*32); }

  for (int nt = 0; nt < NTILES; ++nt){
    if (nt + 1 < NTILES){
      #pragma unroll
      for (int q = 0; q < 4; ++q){
        bhn[q] = *(const bf16x8*)(Bph + (nt+1)*2048 + q*32);
        bln[q] = *(const bf16x8*)(Bpl + (nt+1)*2048 + q*32);
      }
    }
    f32x4 acc = (f32x4){0.f,0.f,0.f,0.f};
    #pragma unroll
    for (int q = 0; q < 4; ++q){
      acc = __builtin_amdgcn_mfma_f32_16x16x32_bf16(al[q], bh[q], acc, 0, 0, 0);
      acc = __builtin_amdgcn_mfma_f32_16x16x32_bf16(ah[q], bl[q], acc, 0, 0, 0);
      acc = __builtin_amdgcn_mfma_f32_16x16x32_bf16(ah[q], bh[q], acc, 0, 0, 0);
    }
    const int n = nt*16 + c15;
    const float bv = bias[n];
    #pragma unroll
    for (int i = 0; i < 4; ++i){
      float v = acc[i] + bv;
      if (ACT == 1) v = tanh_f(v);
      else if (ACT == 2) v = sigmoid_f(v);
      const size_t m = mbase + q4*4 + i;
      if (OUTKIND == 0){
        CoutF[m*(size_t)(NTILES*16) + n] = v;
      } else if (OUTKIND == 1){
        CoutF[m*1024 + (size_t)(n & 255)*4 + (size_t)(n >> 8)] = v;
      } else {
        size_t o = m*(size_t)(NTILES*16) + n;
        u16 hh = f2bf(v); CoutHi[o] = hh; CoutLo[o] = f2bf(v - bf2f(hh));
      }
    }
    #pragma unroll
    for (int q = 0; q < 4; ++q){ bh[q] = bhn[q]; bl[q] = bln[q]; }
  }
}

// ---------------- K3: the scan — round-0 structure, swap-publish experiment ----------------
// 16 WGs; (g,s) = (blockIdx&3, blockIdx>>2). One chain-slot per WG (proven
// register footprint). Exchange: tagged u64 words on hXM, agent scope.
// Publish uses global_atomic_swap (performed AT the MALL coherence point,
// cannot linger in write-coalescing buffers) — testing whether store-drain
// latency was the dominant term of round-0's 3.3us/step. Consumer polls with
// agent-scope loads until all 32 tags match (correct under any timing).
__global__ __launch_bounds__(256, 1) void k_scan(
    const u16* __restrict__ WhT, const float* __restrict__ xwG, const float* __restrict__ jG,
    const float* __restrict__ Wc, const float* __restrict__ h0, const float* __restrict__ c0in,
    const float* __restrict__ Wlin, const float* __restrict__ blin,
    u64* __restrict__ hXM, float* __restrict__ stateF,
    float* __restrict__ out, int T0, int SC, int FINAL)
{
  const int g = blockIdx.x & 3;
  const int s = blockIdx.x >> 2;

  const int tid  = threadIdx.x;
  const int lane = tid & 63;
  const int w    = tid >> 6;
  const int c15  = lane & 15;
  const int q4   = lane >> 4;
  const int ghid = s*64 + w*16 + c15;
  const int FIRST = (T0 == 0);

  // Wh fragments for this wave's 16 cols x 4 gates (128 VGPRs)
  bf16x8 Bf[4][8];
  {
    const u16* bp = WhT + (size_t)ghid*256 + q4*8;
    #pragma unroll
    for (int gt = 0; gt < 4; ++gt)
      #pragma unroll
      for (int q = 0; q < 8; ++q)
        Bf[gt][q] = *(const bf16x8*)(bp + (size_t)gt*65536 + q*32);
  }

  float creg[4], hreg[4];
  #pragma unroll
  for (int i = 0; i < 4; ++i){
    int r = q4*4 + i;
    if (FIRST){
      creg[i] = c0in[(size_t)(g*16 + r)*256 + ghid];
      hreg[i] = h0[(size_t)(g*16 + r)*256 + ghid];
    } else {
      creg[i] = stateF[(size_t)(g*16 + r)*256 + ghid];
      hreg[i] = stateF[16384 + (size_t)(g*16 + r)*256 + ghid];
    }
  }
  const float wc0 = Wc[ghid], wc1 = Wc[256 + ghid], wc2 = Wc[512 + ghid];

  const int P = s*32 + w*8 + (c15 >> 1);   // col-pair index this lane stores

  // xw/j register prefetch (one step ahead; ping-pong arrays, no copies)
  f32x4 xqA[4], xqB[4]; float jvA[4], jvB[4];
  auto ldxw = [&](int tn, f32x4* xq, float* jv){
    const float* xwp = xwG + ((size_t)tn*64 + g*16)*1024 + (size_t)ghid*4;
    const float* jp  = jG  + ((size_t)tn*64 + g*16)*256 + ghid;
    #pragma unroll
    for (int i = 0; i < 4; ++i){
      int r = q4*4 + i;
      xq[i] = *(const f32x4*)(xwp + (size_t)r*1024);
      jv[i] = jp[(size_t)r*256];
    }
  };
  ldxw(0, xqA, jvA);

  auto step = [&](int t, f32x4* xq, float* jv, f32x4* xqN, float* jvN){
    const unsigned T = (unsigned)(T0 + t);
    const int rb = (int)((T + 3) & 3);
    const int wb = (int)(T & 3);
    const u64* hrM = hXM + (size_t)(rb*4 + g)*2048 + c15;

    u64 d[8][4];
    for(;;){
      #pragma unroll
      for (int q = 0; q < 8; ++q)
        #pragma unroll
        for (int jj = 0; jj < 4; ++jj)
          d[q][jj] = agld64(hrM + (q*16 + q4*4 + jj)*16);
      bool ok = true;
      #pragma unroll
      for (int q = 0; q < 8; ++q)
        #pragma unroll
        for (int jj = 0; jj < 4; ++jj)
          ok &= ((u32)(d[q][jj] >> 32) == T);
      if (ok) break;
    }

    bf16x8 Af[8];
    #pragma unroll
    for (int q = 0; q < 8; ++q){
      union { u32 dd[4]; bf16x8 v; } cv;
      #pragma unroll
      for (int jj = 0; jj < 4; ++jj) cv.dd[jj] = (u32)d[q][jj];
      Af[q] = cv.v;
    }

    // issue next step's xw/j now: vmcnt in-order => by the time t+1's poll
    // succeeds these are complete; first use waits for free.
    if (t + 1 < SC) ldxw(t + 1, xqN, jvN);

    f32x4 acc[4];
    #pragma unroll
    for (int gt = 0; gt < 4; ++gt) acc[gt] = (f32x4){0.f,0.f,0.f,0.f};
    #pragma unroll
    for (int q = 0; q < 8; ++q)
      #pragma unroll
      for (int gt = 0; gt < 4; ++gt)
        acc[gt] = __builtin_amdgcn_mfma_f32_16x16x32_bf16(Af[q], Bf[gt][q], acc[gt], 0, 0, 0);

    u16 hb[4];
    #pragma unroll
    for (int i = 0; i < 4; ++i){
      float ip = acc[0][i] + xq[i][0] + creg[i]*wc0;
      float fp = acc[1][i] + xq[i][1] + creg[i]*wc1;
      float gp = acc[2][i] + xq[i][2];
      float op = acc[3][i] + xq[i][3] + creg[i]*wc2;
      float it2 = sigmoid_f(ip);
      float ft = sigmoid_f(fp);
      float gt = tanh_f(gp);
      float ot = sigmoid_f(op);
      float chat = ft*creg[i] + it2*gt;
      float cn = creg[i] + jv[i]*(chat - creg[i]);
      float hhat = ot*tanh_f(chat);
      float hn = hreg[i] + jv[i]*(hhat - hreg[i]);
      creg[i] = cn; hreg[i] = hn;
      hb[i] = f2bf(hn);
    }

    u32 a = (u32)hb[0] | ((u32)hb[1] << 16);
    u32 b = (u32)hb[2] | ((u32)hb[3] << 16);
    u32 pa = (u32)__shfl_xor((int)a, 1, 64);
    u32 pb = (u32)__shfl_xor((int)b, 1, 64);
    u64* hwM = hXM + (size_t)(wb*4 + g)*2048 + (size_t)P*16;
    const u64 tag = ((u64)(T + 1)) << 32;
    if ((lane & 1) == 0){
      agxchg64(hwM + q4*4 + 0, tag | (u64)((a & 0xffffu) | ((pa & 0xffffu) << 16)));
      agxchg64(hwM + q4*4 + 1, tag | (u64)((a >> 16) | (pa & 0xffff0000u)));
    } else {
      agxchg64(hwM + q4*4 + 2, tag | (u64)((pb & 0xffffu) | ((b & 0xffffu) << 16)));
      agxchg64(hwM + q4*4 + 3, tag | (u64)((pb >> 16) | (b & 0xffff0000u)));
    }
    asm volatile("" ::: "memory");   // keep stores inside this step
  };

  for (int t = 0; t < SC; t += 2){   // SC is always even
    step(t,     xqA, jvA, xqB, jvB);
    step(t + 1, xqB, jvB, xqA, jvA);
  }

  // persist f32 state for next chunk (kernel-boundary flush makes it visible)
  if (!FINAL){
    #pragma unroll
    for (int i = 0; i < 4; ++i){
      int r = q4*4 + i;
      stateF[(size_t)(g*16 + r)*256 + ghid] = creg[i];
      stateF[16384 + (size_t)(g*16 + r)*256 + ghid] = hreg[i];
    }
  }

  // epilogue on final chunk: out = h_T @ Wlin + blin  (slot-0 WG per group)
  if (FINAL && s == 0){
    __shared__ float hF[16*256];
    const unsigned tgt = (unsigned)NS;     // h_T carries tag NS in buffer 3
    for (int idx = tid; idx < 2048; idx += 256){
      int r = idx >> 7, p = idx & 127;
      const u64* ap = hXM + (size_t)(3*4 + g)*2048 + p*16 + r;
      u64 v;
      do { v = agld64(ap); } while ((u32)(v >> 32) != tgt);
      hF[r*256 + 2*p]     = bf2f((u16)v);
      hF[r*256 + 2*p + 1] = bf2f((u16)(v >> 16));
    }
    __syncthreads();
    for (int idx = tid; idx < 1024; idx += 256){
      int r = idx >> 6, dcol = idx & 63;
      float aacc = blin[dcol];
      for (int k = 0; k < 256; ++k)
        aacc = fmaf(hF[r*256 + k], Wlin[k*64 + dcol], aacc);
      out[(size_t)(g*16 + r)*64 + dcol] = aacc;
    }
  }
}

// ---------------- host ----------------
extern "C" void kernel_launch(void* const* d_in, const int* in_sizes, int n_in,
                              void* d_out, int out_size, void* d_ws, size_t ws_size,
                              hipStream_t stream)
{
  (void)in_sizes; (void)n_in;
  const float* event = (const float*)d_in[0];
  const float* vc    = (const float*)d_in[2];
  const float* vn    = (const float*)d_in[3];
  const float* h0    = (const float*)d_in[4];
  const float* c0v   = (const float*)d_in[5];
  const float* Wx    = (const float*)d_in[6];
  const float* Wh    = (const float*)d_in[7];
  const float* Wc    = (const float*)d_in[8];
  const float* bias  = (const float*)d_in[9];
  const float* Ve    = (const float*)d_in[10];
  const float* Vc    = (const float*)d_in[11];
  const float* Vn    = (const float*)d_in[12];
  const float* Wlin  = (const float*)d_in[13];
  const float* blin  = (const float*)d_in[14];
  const float* Wef1  = (const float*)d_in[15];
  const float* bef1  = (const float*)d_in[16];
  const float* Wef3  = (const float*)d_in[17];
  const float* bef3  = (const float*)d_in[18];

  int SC = 0;
  const int cands[9] = {4096, 2048, 1024, 512, 256, 128, 64, 32, 16};
  for (int i = 0; i < 9; ++i){
    if (OFF_CH + (size_t)cands[i]*CH_BYTES_PER_SC <= ws_size){ SC = cands[i]; break; }
  }
  if (SC == 0){
    hipMemsetAsync(d_out, 0, (size_t)out_size*sizeof(float), stream);
    return;
  }
  const int C = NS / SC;

  char* ws = (char*)d_ws;
  u64*   hXM    = (u64*)(ws + OFF_HXM);
  float* stateF = (float*)(ws + OFF_STATE);
  u16* WhT   = (u16*)(ws + OFF_WHT);
  u16* WxTh  = (u16*)(ws + OFF_WXTH);
  u16* WxTl  = (u16*)(ws + OFF_WXTL);
  u16* Wef1h = (u16*)(ws + OFF_WEF1H);
  u16* Wef1l = (u16*)(ws + OFF_WEF1L);
  u16* Wef3h = (u16*)(ws + OFF_WEF3H);
  u16* Wef3l = (u16*)(ws + OFF_WEF3L);
  char* ch = ws + OFF_CH;
  u16* sHi  = (u16*)ch;
  u16* sLo  = (u16*)(ch + (size_t)SC*16384);
  u16* xHi  = (u16*)(ch + (size_t)SC*32768);
  u16* xLo  = (u16*)(ch + (size_t)SC*49152);
  u16* e1Hi = (u16*)(ch + (size_t)SC*65536);
  u16* e1Lo = (u16*)(ch + (size_t)SC*81920);
  float* xwG = (float*)(ch + (size_t)SC*98304);
  float* jG  = (float*)(ch + (size_t)SC*360448);

  k_prep<<<1728, 256, 0, stream>>>(Wh, Wx, Wef1, Wef3, WhT, WxTh, WxTl,
                                   Wef1h, Wef1l, Wef3h, Wef3l);
  k_seed<<<32, 256, 0, stream>>>(h0, hXM);

  for (int c = 0; c < C; ++c){
    const int c0 = c * SC;
    k_embed<<<SC*4, 256, 0, stream>>>(event, vc, vn, Ve, Vc, Vn, sHi, sLo, xHi, xLo, c0);
    k_gemm<0,1,64><<<SC, 256, 0, stream>>>(xHi, xLo, WxTh, WxTl, bias, xwG, nullptr, nullptr);
    k_gemm<1,2,8><<<SC, 256, 0, stream>>>(sHi, sLo, Wef1h, Wef1l, bef1, nullptr, e1Hi, e1Lo);
    k_gemm<2,0,16><<<SC, 256, 0, stream>>>(e1Hi, e1Lo, Wef3h, Wef3l, bef3, jG, nullptr, nullptr);
    k_scan<<<16, 256, 0, stream>>>(WhT, xwG, jG, Wc, h0, c0v, Wlin, blin,
                                   hXM, stateF, (float*)d_out, c0, SC, (c == C-1) ? 1 : 0);
  }
}